// Round 8
// baseline (99.325 us; speedup 1.0000x reference)
//
#include <hip/hip_runtime.h>
#include <hip/hip_bf16.h>

// world_state_encoder: out[b, beaker*4+slot, :] = color_emb[X[b, beaker*5+1+slot], :]
// B=32768, 7 beakers, 4 color slots, D=128 -> out is [B, 3584] f32 (470 MB).
//
// History: R1 per-row blocks 147us; R2 grid-stride 110us; R3 LDS-staged idx
// 96.8; R5 nt@28waves 98.8; R6 LDS-only loop 97.0; R7 memset-geometry
// (256thr, 4 waves/CU) 96.1. Four disjoint structures converge at 4.85-4.9
// TB/s => body+geometry exhausted. Two-point fit vs the harness fill kernel
// (1879MB@270us) gives body-BW ~= spec with ~35us fixed/ramp cost T0.
//
// R8 (last untested combo): nontemporal stores in the LOW-stream-count
// regime. R5's nt ran at 28 waves/CU where stream count saturated the L2
// write path regardless; here 4 waves/CU x nt bypasses L2 write-allocate
// with few deep streams (fill's own regime), unroll 16 -> 16 KB in flight
// per wave. If neutral: T0 model stands, declare roofline.

#define NUM_BEAKERS 7
#define ENTRIES_PER_BEAKER 5
#define ROW_INTS (NUM_BEAKERS * ENTRIES_PER_BEAKER)   // 35
#define COLOR_DIM 128
#define GROUPS 28                                     // 7 beakers * 4 color slots
#define F4_PER_ROW (GROUPS * COLOR_DIM / 4)           // 896 float4 per row
#define NTHREADS 256                                  // memset-clone geometry
#define CHUNK 128                                     // rows per block (B/grid)

typedef float f32x4 __attribute__((ext_vector_type(4)));

__global__ __launch_bounds__(NTHREADS, 1) void world_state_encoder_kernel(
        const int* __restrict__ X,          // [B, 35] int32
        const float* __restrict__ emb,      // [7, 128] f32
        float* __restrict__ out,            // [B, 3584] f32
        int B) {
    const int tid = threadIdx.x;            // 0..255

    __shared__ int   xs[CHUNK * ROW_INTS];  // 17920 B raw X slice
    __shared__ float semb[7 * COLOR_DIM];   // 3584 B embedding table

    const f32x4* __restrict__ sembf4 = reinterpret_cast<const f32x4*>(semb);
    f32x4* __restrict__ outf4 = reinterpret_cast<f32x4*>(out);

    for (int i = tid; i < 7 * COLOR_DIM; i += NTHREADS)
        semb[i] = emb[i];

    for (int b0 = blockIdx.x * CHUNK; b0 < B; b0 += gridDim.x * CHUNK) {
        const int rows  = min(CHUNK, B - b0);
        const int nints = rows * ROW_INTS;

        __syncthreads();                    // xs reuse guard / semb ready
        for (int i = tid; i < nints; i += NTHREADS)
            xs[i] = X[b0 * ROW_INTS + i];   // one coalesced 17.5 KB read
        __syncthreads();

        f32x4* __restrict__ dst = outf4 + (size_t)b0 * F4_PER_ROW;
        const int nj = rows * F4_PER_ROW;   // 114688 for full chunk
        #pragma unroll 16
        for (int j = tid; j < nj; j += NTHREADS) {
            const int r  = j / F4_PER_ROW;          // magic-mul, j < 2^17
            const int t  = j - r * F4_PER_ROW;      // 0..895
            const int g  = t >> 5;                  // 0..27
            const int d4 = t & 31;
            const int xo = (g >> 2) * ENTRIES_PER_BEAKER + (g & 3) + 1;
            const int id = xs[r * ROW_INTS + xo];   // LDS broadcast-ish
            const f32x4 v = sembf4[id * (COLOR_DIM / 4) + d4];
            __builtin_nontemporal_store(v, &dst[j]);  // nt: bypass L2 write-alloc
        }
    }
}

extern "C" void kernel_launch(void* const* d_in, const int* in_sizes, int n_in,
                              void* d_out, int out_size, void* d_ws, size_t ws_size,
                              hipStream_t stream) {
    const int*   X   = (const int*)d_in[0];     // [B, 35] int32
    const float* emb = (const float*)d_in[1];   // [7, 128] f32
    float*       out = (float*)d_out;           // [B, 3584] f32

    const int B = in_sizes[0] / ROW_INTS;       // 32768

    const int nchunks = (B + CHUNK - 1) / CHUNK;    // 256 for B=32768
    const int grid = (nchunks < 256) ? nchunks : 256;  // 1 block/CU, 4 waves/CU
    world_state_encoder_kernel<<<grid, NTHREADS, 0, stream>>>(X, emb, out, B);
}